// Round 10
// baseline (2641.964 us; speedup 1.0000x reference)
//
#include <hip/hip_runtime.h>
#include <hip/hip_bf16.h>

#define BB 128
#define NV 512
#define NN (BB*NV)
#define EPER_C 8192
#define E_TOT (BB*EPER_C)
#define BN_EPS_F 1e-5f

typedef unsigned int u32;
typedef unsigned short u16;

__device__ __forceinline__ float bfu2f_lo(u32 w) { return __uint_as_float(w << 16); }
__device__ __forceinline__ float bfu2f_hi(u32 w) { return __uint_as_float(w & 0xFFFF0000u); }
__device__ __forceinline__ u16 f2bf(float f) {
    u32 u = __float_as_uint(f);
    u32 r = (u + 0x7FFFu + ((u >> 16) & 1u)) >> 16;
    return (u16)r;
}
__device__ __forceinline__ u32 pack2(float a, float b) {
    return (u32)f2bf(a) | ((u32)f2bf(b) << 16);
}
__device__ __forceinline__ float f16u2f(u16 h) {
    const u32 s = ((u32)h & 0x8000u) << 16;
    const u32 e = (h >> 10) & 0x1Fu;
    const u32 m = h & 0x3FFu;
    if (e == 0u) {
        float v = (float)m * 5.9604644775390625e-8f;
        return s ? -v : v;
    }
    if (e == 31u) return __uint_as_float(s | 0x7F800000u | (m << 13));
    return __uint_as_float(s | ((e + 112u) << 23) | (m << 13));
}
__device__ __forceinline__ float san(float v) {
    if (!(v == v)) return 0.f;
    return fminf(fmaxf(v, -1e30f), 1e30f);
}

// H storage: hf32=1 fp32, hf32=0 packed bf16. i2 = pair index (2 elems).
__device__ __forceinline__ float2 h_ld2(const u32* H, size_t i2, int hf32) {
    float2 v;
    if (hf32) {
        v = ((const float2*)H)[i2];
    } else {
        const u32 w = H[i2];
        v.x = bfu2f_lo(w);
        v.y = bfu2f_hi(w);
    }
    return v;
}
__device__ __forceinline__ void h_st2(u32* H, size_t i2, float a, float b, int hf32) {
    if (hf32) {
        float2 v;
        v.x = a;
        v.y = b;
        ((float2*)H)[i2] = v;
    } else {
        H[i2] = pack2(a, b);
    }
}
__device__ __forceinline__ float h_ld1(const u32* H, size_t i, int hf32) {
    if (hf32) return ((const float*)H)[i];
    return __uint_as_float(((u32)((const u16*)H)[i]) << 16);
}

// OUTPUT IS FLOAT32 (reference returns jnp.float32)
__global__ void fill_out_kernel(float* o, float v) {
    int i = blockIdx.x * 256 + threadIdx.x;
    if (i < 257) o[i] = v;
}

// flags area (u32): [0..7] loss scalars (fp32), [8] int32 flag, [9] float class
__global__ void init_kernel(u32* p, int n) {
    int i = blockIdx.x * 256 + threadIdx.x;
    if (i < n) p[i] = 0u;
}

__global__ void probe_kernel(const u32* g, const u32* e, u32* flags) {
    if (threadIdx.x == 0) {
        const u32 w = g[0];
        u32 cls = 0u;                        // bf16 pair 0x3F803F80
        if (w == 0x3F800000u) cls = 1u;      // fp32 (expected)
        else if (w == 0x3C003C00u) cls = 2u; // fp16 pair
        flags[9] = cls;
        u32 acc = 0u;
        for (int i = 0; i < 2048; ++i) acc |= e[2 * i + 1];
        flags[8] = (acc != 0u) ? 1u : 0u;    // 0 => int64 (expected)
    }
}

__device__ __forceinline__ int ld_src(const int* e, int is64, size_t i) {
    return (is64 ? e[2 * i] : e[i]) & (NN - 1);
}
__device__ __forceinline__ int ld_dst(const int* e, int is64, size_t i) {
    return (is64 ? e[2 * ((size_t)E_TOT + i)] : e[(size_t)E_TOT + i]) & (NN - 1);
}
__device__ __forceinline__ int ld_y(const int* y, int is64, int bi) {
    return (is64 ? y[2 * bi] : y[bi]) & 1;
}

__global__ void cvt_kernel(const u16* s16, const float* s32, float* dst, int n,
                           const u32* flags) {
    const int i = blockIdx.x * 256 + threadIdx.x;
    if (i >= n) return;
    const u32 cls = flags[9];
    float v;
    if (cls == 1u) v = s32[i];
    else if (cls == 2u) v = f16u2f(s16[i]);
    else v = __uint_as_float(((u32)s16[i]) << 16);
    dst[i] = v;
}

// GEMM: Y[n][c] = sum_k X[n][k] * W[k][c], K=C=128.
// xmode=1: X is the input x, dtype per flags[9]. xmode=0: X is H storage (hf32).
__global__ __launch_bounds__(256) void gemm_k(const u32* __restrict__ X2,
                                              const float* __restrict__ Wc,
                                              u32* __restrict__ Y2,
                                              const u32* __restrict__ flags,
                                              int xmode, int hf32) {
    __shared__ float xs[64 * 129];
    __shared__ float wsm[128 * 32];
    const int n0 = blockIdx.x * 64;
    const int c0 = blockIdx.y * 32;
    const int t = threadIdx.x;
    if (xmode) {
        const u32 cls = flags[9];
        if (cls == 1u) {
            for (int idx = t; idx < 64 * 32; idx += 256) {
                const int r = idx >> 5, q = idx & 31;
                const float4 v = ((const float4*)X2)[(size_t)(n0 + r) * 32 + q];
                float* xd = &xs[r * 129 + q * 4];
                xd[0] = v.x; xd[1] = v.y; xd[2] = v.z; xd[3] = v.w;
            }
        } else if (cls == 2u) {
            for (int idx = t; idx < 64 * 16; idx += 256) {
                const int r = idx >> 4, q = idx & 15;
                const uint4 v = ((const uint4*)X2)[(size_t)(n0 + r) * 16 + q];
                float* xd = &xs[r * 129 + q * 8];
                xd[0] = f16u2f((u16)(v.x & 0xFFFFu)); xd[1] = f16u2f((u16)(v.x >> 16));
                xd[2] = f16u2f((u16)(v.y & 0xFFFFu)); xd[3] = f16u2f((u16)(v.y >> 16));
                xd[4] = f16u2f((u16)(v.z & 0xFFFFu)); xd[5] = f16u2f((u16)(v.z >> 16));
                xd[6] = f16u2f((u16)(v.w & 0xFFFFu)); xd[7] = f16u2f((u16)(v.w >> 16));
            }
        } else {
            for (int idx = t; idx < 64 * 16; idx += 256) {
                const int r = idx >> 4, q = idx & 15;
                const uint4 v = ((const uint4*)X2)[(size_t)(n0 + r) * 16 + q];
                float* xd = &xs[r * 129 + q * 8];
                xd[0] = bfu2f_lo(v.x); xd[1] = bfu2f_hi(v.x);
                xd[2] = bfu2f_lo(v.y); xd[3] = bfu2f_hi(v.y);
                xd[4] = bfu2f_lo(v.z); xd[5] = bfu2f_hi(v.z);
                xd[6] = bfu2f_lo(v.w); xd[7] = bfu2f_hi(v.w);
            }
        }
    } else {
        for (int idx = t; idx < 64 * 64; idx += 256) {
            const int r = idx >> 6, q = idx & 63;
            const float2 v = h_ld2(X2, (size_t)(n0 + r) * 64 + q, hf32);
            xs[r * 129 + 2 * q] = v.x;
            xs[r * 129 + 2 * q + 1] = v.y;
        }
    }
    for (int idx = t; idx < 128 * 32; idx += 256) {
        const int k = idx >> 5, cc = idx & 31;
        wsm[idx] = Wc[(size_t)k * 128 + c0 + cc];
    }
    __syncthreads();
    const int tx = t & 15, ty = t >> 4;
    const int cl = tx * 2, rl = ty * 4;
    float a00 = 0.f, a01 = 0.f, a10 = 0.f, a11 = 0.f;
    float a20 = 0.f, a21 = 0.f, a30 = 0.f, a31 = 0.f;
    for (int k = 0; k < 128; ++k) {
        const float w0 = wsm[k * 32 + cl];
        const float w1 = wsm[k * 32 + cl + 1];
        const float x0 = xs[(rl + 0) * 129 + k];
        const float x1 = xs[(rl + 1) * 129 + k];
        const float x2 = xs[(rl + 2) * 129 + k];
        const float x3 = xs[(rl + 3) * 129 + k];
        a00 += x0 * w0; a01 += x0 * w1;
        a10 += x1 * w0; a11 += x1 * w1;
        a20 += x2 * w0; a21 += x2 * w1;
        a30 += x3 * w0; a31 += x3 * w1;
    }
    const size_t pc = (size_t)(c0 >> 1) + tx;
    h_st2(Y2, (size_t)(n0 + rl + 0) * 64 + pc, a00, a01, hf32);
    h_st2(Y2, (size_t)(n0 + rl + 1) * 64 + pc, a10, a11, hf32);
    h_st2(Y2, (size_t)(n0 + rl + 2) * 64 + pc, a20, a21, hf32);
    h_st2(Y2, (size_t)(n0 + rl + 3) * 64 + pc, a30, a31, hf32);
}

// scatter: h[dst] += m[src], +bias, relu, in place; also BN column sums.
// Block-diagonal graph: block (batch, 16-col chunk) touches only its own slice.
// LDS stride 17 floats/node: bank = (17d+j)&31 spreads atomics over all banks
// (stride 16 put 64 lanes on 2 banks -> ~32-way atomic serialization).
__global__ __launch_bounds__(256) void scatter_k(const int* __restrict__ eidx,
                                                 const u32* __restrict__ flags,
                                                 const float* __restrict__ bias,
                                                 u32* M2,
                                                 float* __restrict__ bnacc,
                                                 int col_base, int hf32) {
    __shared__ float acc[512 * 17];  // 34 KB
    const int bi = blockIdx.x >> 3;
    const int fc = blockIdx.x & 7;
    const int t = threadIdx.x;
    const int is64 = (flags[8] == 0u);
    for (int i = t; i < 512 * 17; i += 256) acc[i] = 0.f;
    __syncthreads();
    const size_t eb = (size_t)bi * EPER_C;
    for (int e = t; e < EPER_C; e += 256) {
        const int s = ld_src(eidx, is64, eb + e);
        const int d = ld_dst(eidx, is64, eb + e) & 511;
        const size_t pbase = (size_t)s * 64 + fc * 8;
        float* a = &acc[d * 17];
#pragma unroll
        for (int q = 0; q < 8; ++q) {
            const float2 v = h_ld2(M2, pbase + q, hf32);
            atomicAdd(a + 2 * q + 0, v.x);
            atomicAdd(a + 2 * q + 1, v.y);
        }
    }
    __syncthreads();
    float s0 = 0.f, s1 = 0.f, q0 = 0.f, q1 = 0.f;
    const int p = t & 7;
    const float b0 = bias[fc * 16 + 2 * p + 0];
    const float b1 = bias[fc * 16 + 2 * p + 1];
    for (int j = 0; j < 16; ++j) {
        const int l = (t >> 3) + j * 32;
        float v0 = san(acc[l * 17 + 2 * p + 0] + b0);
        float v1 = san(acc[l * 17 + 2 * p + 1] + b1);
        v0 = v0 > 0.f ? v0 : 0.f;
        v1 = v1 > 0.f ? v1 : 0.f;
        h_st2(M2, (size_t)(bi * 512 + l) * 64 + fc * 8 + p, v0, v1, hf32);
        s0 += v0; s1 += v1; q0 += v0 * v0; q1 += v1 * v1;
    }
    __syncthreads();
    acc[4 * t + 0] = s0;
    acc[4 * t + 1] = s1;
    acc[4 * t + 2] = q0;
    acc[4 * t + 3] = q1;
    __syncthreads();
    if (t < 32) {
        const int pp = t & 7;
        const int b = (t >> 3) & 1;
        const int sg = (t >> 4) & 1;
        float sum = 0.f;
        for (int r = 0; r < 32; ++r) {
            const int tt = (r << 3) | pp;
            sum += acc[4 * tt + 2 * sg + b];
        }
        atomicAdd(&bnacc[(size_t)(col_base + fc * 16 + 2 * pp + b) * 2 + sg], sum);
    }
}

__global__ __launch_bounds__(384) void bn2_kernel(const float* __restrict__ bnacc,
                                                  const float* __restrict__ gamma,
                                                  const float* __restrict__ beta,
                                                  float* __restrict__ scaleA,
                                                  float* __restrict__ shiftA) {
    const int c = threadIdx.x;
    const float s = bnacc[c * 2 + 0];
    const float s2 = bnacc[c * 2 + 1];
    const float inv_n = 1.f / (float)NN;
    const float mu = san(s * inv_n);
    float var = san(s2 * inv_n - mu * mu);
    var = var > 0.f ? var : 0.f;
    const float sc = san(gamma[c] / sqrtf(var + BN_EPS_F));
    scaleA[c] = sc;
    shiftA[c] = san(beta[c] - mu * sc);
}

__global__ __launch_bounds__(256) void dist_kernel(const u32* __restrict__ h1,
                                                   const u32* __restrict__ h2,
                                                   const u32* __restrict__ h3,
                                                   const float* __restrict__ kc,
                                                   const float* __restrict__ scaleA,
                                                   const float* __restrict__ shiftA,
                                                   float4* __restrict__ Sf4, int hf32) {
    __shared__ float k2f[15 * 384];
    __shared__ float scl[384], shf[384];
    __shared__ float ksq[15];
    const int t = threadIdx.x;
    for (int i = t; i < 15 * 384; i += 256) k2f[i] = kc[i];
    for (int i = t; i < 384; i += 256) {
        scl[i] = scaleA[i];
        shf[i] = shiftA[i];
    }
    __syncthreads();
    if (t < 15) {
        float q = 0.f;
        for (int c2 = 0; c2 < 384; ++c2) {
            const float v = k2f[t * 384 + c2];
            q += v * v;
        }
        ksq[t] = q;
    }
    __syncthreads();
    const int n = blockIdx.x * 256 + t;
    float acc[15];
#pragma unroll
    for (int j = 0; j < 15; ++j) acc[j] = 0.f;
    float xq = 0.f;
#pragma unroll
    for (int pL = 0; pL < 3; ++pL) {
        const u32* hp = (pL == 0) ? h1 : (pL == 1) ? h2 : h3;
        const size_t rowp = (size_t)n * 64;
        for (int q8 = 0; q8 < 16; ++q8) {
            float xv[8];
#pragma unroll
            for (int j2 = 0; j2 < 4; ++j2) {
                const float2 v = h_ld2(hp, rowp + q8 * 4 + j2, hf32);
                xv[2 * j2] = v.x;
                xv[2 * j2 + 1] = v.y;
            }
            const int c = pL * 128 + q8 * 8;
#pragma unroll
            for (int i = 0; i < 8; ++i) {
                const float x = xv[i] * scl[c + i] + shf[c + i];
                xv[i] = x;
                xq += x * x;
            }
#pragma unroll
            for (int j = 0; j < 15; ++j) {
                const float* kr = &k2f[j * 384 + c];
                float a = acc[j];
#pragma unroll
                for (int i = 0; i < 8; ++i) a += xv[i] * kr[i];
                acc[j] = a;
            }
        }
    }
    float dist[15];
#pragma unroll
    for (int j = 0; j < 15; ++j) {
        float d2 = san(ksq[j] + xq - 2.f * acc[j]);
        d2 = d2 > 0.f ? d2 : 0.f;
        dist[j] = 1.f / (1.f + d2);
    }
    float S0 = 0.f, S1 = 0.f, S2 = 0.f;
#pragma unroll
    for (int h = 0; h < 5; ++h) {
        const float a = dist[h * 3 + 0], b = dist[h * 3 + 1], cd = dist[h * 3 + 2];
        const float inv = 1.f / fmaxf(a + b + cd, 1e-30f);
        S0 += a * inv;
        S1 += b * inv;
        S2 += cd * inv;
    }
    float4 o;
    o.x = san(S0); o.y = san(S1); o.z = san(S2); o.w = 0.f;
    Sf4[n] = o;
}

__global__ __launch_bounds__(256) void sagg_kernel(const int* __restrict__ eidx,
                                                   const u32* __restrict__ flags,
                                                   const float4* __restrict__ Sf4,
                                                   const int* __restrict__ y,
                                                   int* __restrict__ nodeK,
                                                   float* __restrict__ nodeW,
                                                   float* __restrict__ scal) {
    __shared__ float sacc[512 * 3];
    __shared__ unsigned int degc[512];
    __shared__ float rA[256], rB[256];
    const int bi = blockIdx.x;
    const int t = threadIdx.x;
    const int is64 = (flags[8] == 0u);
    for (int i = t; i < 512 * 3; i += 256) sacc[i] = 0.f;
    for (int i = t; i < 512; i += 256) degc[i] = 0u;
    __syncthreads();
    const size_t eb = (size_t)bi * EPER_C;
    for (int e = t; e < EPER_C; e += 256) {
        const int sg = ld_src(eidx, is64, eb + e);
        const int dg = ld_dst(eidx, is64, eb + e);
        const int sl = sg & 511;
        const int dl = dg & 511;
        const float4 sv = Sf4[dg];
        atomicAdd(&sacc[sl * 3 + 0], sv.x);
        atomicAdd(&sacc[sl * 3 + 1], sv.y);
        atomicAdd(&sacc[sl * 3 + 2], sv.z);
        atomicAdd(&degc[sl], 1u);
        atomicAdd(&degc[dl], 1u);
    }
    __syncthreads();
    float mfAcc = 0.f, slAcc = 0.f;
    for (int l = t; l < 512; l += 256) {
        const float cnt = (float)degc[l];
        const float degf = cnt > 0.f ? cnt * 0.5f : 1.f;
        const float inv = 1.f / degf;
        const float r0 = san(sacc[l * 3 + 0] * inv);
        const float r1 = san(sacc[l * 3 + 1] * inv);
        const float r2 = san(sacc[l * 3 + 2] * inv);
        int am = 0;
        float mx = r0;
        if (r1 > mx) { mx = r1; am = 1; }
        if (r2 > mx) { mx = r2; am = 2; }
        const float e0 = expf(r0 - mx), e1 = expf(r1 - mx), e2 = expf(r2 - mx);
        const float g = san(1.f / (e0 + e1 + e2));
        const int n = bi * 512 + l;
        nodeK[n] = am;
        nodeW[n] = g;
        if (am < 2) {
            mfAcc += 1.f;
            slAcc += g;
        }
    }
    rA[t] = mfAcc;
    rB[t] = slAcc;
    __syncthreads();
    for (int sft = 128; sft > 0; sft >>= 1) {
        if (t < sft) {
            rA[t] += rA[t + sft];
            rB[t] += rB[t + sft];
        }
        __syncthreads();
    }
    if (t == 0) {
        atomicAdd(&scal[ld_y(y, is64, bi)], rA[0]);
        atomicAdd(&scal[2], rB[0]);
    }
}

__global__ __launch_bounds__(256) void ce_kernel(const int* __restrict__ nodeK,
                                                 const float* __restrict__ nodeW,
                                                 const u32* __restrict__ flags,
                                                 const int* __restrict__ y,
                                                 float* __restrict__ scal) {
    const int n = blockIdx.x * 256 + threadIdx.x;
    const int bi = n >> 9;
    const int is64 = (flags[8] == 0u);
    const int kn = nodeK[n];
    float wce = 0.f, wsum = 0.f;
    if (kn >= 0 && kn < 2) {
        const float w = nodeW[n];
        const int yb = ld_y(y, is64, bi);
        const float l0 = (kn == 0) ? w : 0.f;
        const float l1 = (kn == 1) ? w : 0.f;
        const float m = fmaxf(l0, l1);
        const float lz = m + logf(expf(l0 - m) + expf(l1 - m));
        const float ce = lz - ((yb == 0) ? l0 : l1);
        const float bc0 = 1.f + scal[0];
        const float bc1 = 1.f + scal[1];
        const float bmax = fmaxf(bc0, bc1);
        const float wt = bmax / (((yb == 0) ? bc0 : bc1) + 0.001f);
        wce = san(wt * ce);
        wsum = san(wt);
    }
    __shared__ float rA[256], rB[256];
    const int t = threadIdx.x;
    rA[t] = wce;
    rB[t] = wsum;
    __syncthreads();
    for (int sft = 128; sft > 0; sft >>= 1) {
        if (t < sft) {
            rA[t] += rA[t + sft];
            rB[t] += rB[t + sft];
        }
        __syncthreads();
    }
    if (t == 0) {
        atomicAdd(&scal[3], rA[0]);
        atomicAdd(&scal[4], rB[0]);
    }
}

__global__ __launch_bounds__(192) void xp_kernel(const u32* __restrict__ h1,
                                                 const u32* __restrict__ h2,
                                                 const u32* __restrict__ h3,
                                                 const float* __restrict__ scaleA,
                                                 const float* __restrict__ shiftA,
                                                 const int* __restrict__ nodeK,
                                                 const float* __restrict__ nodeW,
                                                 float* __restrict__ xp, int hf32) {
    const int bi = blockIdx.x >> 1;
    const int half = blockIdx.x & 1;
    const int c = half * 192 + threadIdx.x;
    const u32* harr = (c < 128) ? h1 : (c < 256) ? h2 : h3;
    const int cc = c & 127;
    const float sc = scaleA[c], sh = shiftA[c];
    float a0 = 0.f, a1 = 0.f;
    const int nb = bi * 512;
    for (int l = 0; l < 512; ++l) {
        const int kn = nodeK[nb + l];
        if (kn >= 0 && kn < 2) {
            const float w = nodeW[nb + l];
            const float xv = h_ld1(harr, (size_t)(nb + l) * 128 + cc, hf32) * sc + sh;
            if (kn == 0) a0 += w * xv; else a1 += w * xv;
        }
    }
    xp[((size_t)bi * 2 + 0) * 384 + c] = san(a0);
    xp[((size_t)bi * 2 + 1) * 384 + c] = san(a1);
}

__global__ __launch_bounds__(128) void head_kernel(const float* __restrict__ xp,
                                                   const float* __restrict__ lpW,
                                                   const float* __restrict__ l1W,
                                                   const float* __restrict__ l1b,
                                                   const float* __restrict__ l2W,
                                                   const float* __restrict__ l2b,
                                                   float* __restrict__ outp) {
    const int bi = blockIdx.x;
    const int t = threadIdx.x;
    __shared__ float xfl[32];
    __shared__ float hidl[128];
    if (t < 32) {
        const int kk = t >> 4, o = t & 15;
        const float* xr = xp + ((size_t)bi * 2 + kk) * 384;
        float acc = 0.f;
        for (int c2 = 0; c2 < 384; ++c2) acc += xr[c2] * lpW[c2 * 16 + o];
        xfl[t] = san(acc);
    }
    __syncthreads();
    float acc = l1b[t];
    for (int i = 0; i < 32; ++i) acc += xfl[i] * l1W[i * 128 + t];
    hidl[t] = fmaxf(san(acc), 0.f);
    __syncthreads();
    if (t == 0) {
        float L0 = l2b[0], L1v = l2b[1];
        for (int j = 0; j < 128; ++j) {
            const float h = hidl[j];
            L0 += h * l2W[j * 2 + 0];
            L1v += h * l2W[j * 2 + 1];
        }
        L0 = san(L0); L1v = san(L1v);
        const float m = fmaxf(L0, L1v);
        const float ls = m + logf(expf(L0 - m) + expf(L1v - m));
        outp[bi * 2 + 0] = san(L0 - ls);
        outp[bi * 2 + 1] = san(L1v - ls);
    }
}

__global__ void fin_kernel(const float* __restrict__ scal, float* __restrict__ outp) {
    const float cel = san(scal[3] / fmaxf(scal[4], 1e-12f));
    const float total = san(10.f * cel + 0.01f * (scal[2] / (float)BB));
    outp[BB * 2] = total;
}

extern "C" void kernel_launch(void* const* d_in, const int* in_sizes, int n_in,
                              void* d_out, int out_size, void* d_ws, size_t ws_size,
                              hipStream_t stream) {
    (void)in_sizes; (void)n_in; (void)out_size;
    float* outp = (float*)d_out;

    // tail: Sf4 + nodeW + nodeK + xp + scal/flags + bnacc + scale/shift + canon
    const size_t tailW = (size_t)NN * 4 + (size_t)NN + (size_t)NN + 98304 + 16 + 768 + 768 + 66690;
    const size_t needF = 3ull * NN * 128ull * 4ull + tailW * 4ull;
    const size_t needB = 3ull * NN * 128ull * 2ull + tailW * 4ull;
    int hf32;
    if (ws_size >= needF) hf32 = 1;
    else if (ws_size >= needB) hf32 = 0;
    else {
        fill_out_kernel<<<2, 256, 0, stream>>>(outp, 2000.f + (float)(ws_size >> 20));
        return;
    }

    const u32* xw = (const u32*)d_in[0];
    const int* eidx = (const int*)d_in[1];
    const int* y = (const int*)d_in[2];

    const size_t esz = hf32 ? 4u : 2u;
    char* base = (char*)d_ws;
    u32* H1 = (u32*)base;
    u32* H2 = (u32*)(base + (size_t)NN * 128 * esz);
    u32* H3 = (u32*)(base + 2 * (size_t)NN * 128 * esz);
    float* fb = (float*)(base + 3 * (size_t)NN * 128 * esz);
    float4* Sf4 = (float4*)fb;
    float* nodeW = fb + (size_t)NN * 4;
    int* nodeK = (int*)(nodeW + NN);
    float* xp = (float*)(nodeK + NN);
    float* scal = xp + 98304;
    u32* flags = (u32*)scal;
    float* bnacc = scal + 16;
    float* scaleA = bnacc + 768;
    float* shiftA = scaleA + 384;
    float* canon = shiftA + 384;

    init_kernel<<<4, 256, 0, stream>>>(flags, 784);
    probe_kernel<<<1, 64, 0, stream>>>((const u32*)d_in[9], (const u32*)eidx, flags);

    const int psz[14] = {16384, 128, 16384, 128, 16384, 128, 384, 384,
                         5760, 6144, 4096, 128, 256, 2};
    const int pof[14] = {0, 16384, 16512, 32896, 33024, 49408, 49536, 49920,
                         50304, 56064, 62208, 66304, 66432, 66688};
    for (int i = 0; i < 14; ++i) {
        cvt_kernel<<<(psz[i] + 255) / 256, 256, 0, stream>>>(
            (const u16*)d_in[3 + i], (const float*)d_in[3 + i],
            canon + pof[i], psz[i], flags);
    }

    gemm_k<<<dim3(NN / 64, 4), 256, 0, stream>>>(xw, canon + 0, H1, flags, 1, hf32);
    scatter_k<<<BB * 8, 256, 0, stream>>>(eidx, flags, canon + 16384, H1, bnacc, 0, hf32);
    gemm_k<<<dim3(NN / 64, 4), 256, 0, stream>>>(H1, canon + 16512, H2, flags, 0, hf32);
    scatter_k<<<BB * 8, 256, 0, stream>>>(eidx, flags, canon + 32896, H2, bnacc, 128, hf32);
    gemm_k<<<dim3(NN / 64, 4), 256, 0, stream>>>(H2, canon + 33024, H3, flags, 0, hf32);
    scatter_k<<<BB * 8, 256, 0, stream>>>(eidx, flags, canon + 49408, H3, bnacc, 256, hf32);
    bn2_kernel<<<1, 384, 0, stream>>>(bnacc, canon + 49536, canon + 49920, scaleA, shiftA);
    dist_kernel<<<NN / 256, 256, 0, stream>>>(H1, H2, H3, canon + 50304, scaleA, shiftA,
                                              Sf4, hf32);
    sagg_kernel<<<BB, 256, 0, stream>>>(eidx, flags, Sf4, y, nodeK, nodeW, scal);
    ce_kernel<<<NN / 256, 256, 0, stream>>>(nodeK, nodeW, flags, y, scal);
    xp_kernel<<<BB * 2, 192, 0, stream>>>(H1, H2, H3, scaleA, shiftA, nodeK, nodeW, xp, hf32);
    head_kernel<<<BB, 128, 0, stream>>>(xp, canon + 56064, canon + 62208, canon + 66304,
                                        canon + 66432, canon + 66688, outp);
    fin_kernel<<<1, 1, 0, stream>>>(scal, outp);
}

// Round 12
// 1090.758 us; speedup vs baseline: 2.4221x; 2.4221x over previous
//
#include <hip/hip_runtime.h>
#include <hip/hip_bf16.h>

#define BB 128
#define NV 512
#define NN (BB*NV)
#define EPER_C 8192
#define E_TOT (BB*EPER_C)
#define BN_EPS_F 1e-5f

typedef unsigned int u32;
typedef unsigned short u16;

__device__ __forceinline__ float bfu2f_lo(u32 w) { return __uint_as_float(w << 16); }
__device__ __forceinline__ float bfu2f_hi(u32 w) { return __uint_as_float(w & 0xFFFF0000u); }
__device__ __forceinline__ u16 f2bf(float f) {
    u32 u = __float_as_uint(f);
    u32 r = (u + 0x7FFFu + ((u >> 16) & 1u)) >> 16;
    return (u16)r;
}
__device__ __forceinline__ u32 pack2(float a, float b) {
    return (u32)f2bf(a) | ((u32)f2bf(b) << 16);
}
__device__ __forceinline__ float f16u2f(u16 h) {
    const u32 s = ((u32)h & 0x8000u) << 16;
    const u32 e = (h >> 10) & 0x1Fu;
    const u32 m = h & 0x3FFu;
    if (e == 0u) {
        float v = (float)m * 5.9604644775390625e-8f;
        return s ? -v : v;
    }
    if (e == 31u) return __uint_as_float(s | 0x7F800000u | (m << 13));
    return __uint_as_float(s | ((e + 112u) << 23) | (m << 13));
}
__device__ __forceinline__ float san(float v) {
    if (!(v == v)) return 0.f;
    return fminf(fmaxf(v, -1e30f), 1e30f);
}

// H storage: hf32=1 fp32, hf32=0 packed bf16. i2 = pair index (2 elems).
__device__ __forceinline__ float2 h_ld2(const u32* H, size_t i2, int hf32) {
    float2 v;
    if (hf32) {
        v = ((const float2*)H)[i2];
    } else {
        const u32 w = H[i2];
        v.x = bfu2f_lo(w);
        v.y = bfu2f_hi(w);
    }
    return v;
}
__device__ __forceinline__ void h_st2(u32* H, size_t i2, float a, float b, int hf32) {
    if (hf32) {
        float2 v;
        v.x = a;
        v.y = b;
        ((float2*)H)[i2] = v;
    } else {
        H[i2] = pack2(a, b);
    }
}
__device__ __forceinline__ float h_ld1(const u32* H, size_t i, int hf32) {
    if (hf32) return ((const float*)H)[i];
    return __uint_as_float(((u32)((const u16*)H)[i]) << 16);
}

// OUTPUT IS FLOAT32
__global__ void fill_out_kernel(float* o, float v) {
    int i = blockIdx.x * 256 + threadIdx.x;
    if (i < 257) o[i] = v;
}

// flags area (u32): [0..7] loss scalars (fp32), [8] int32 flag, [9] float class
__global__ void init_kernel(u32* p, int n) {
    int i = blockIdx.x * 256 + threadIdx.x;
    if (i < n) p[i] = 0u;
}

__global__ void probe_kernel(const u32* g, const u32* e, u32* flags) {
    if (threadIdx.x == 0) {
        const u32 w = g[0];
        u32 cls = 0u;                        // bf16 pair 0x3F803F80
        if (w == 0x3F800000u) cls = 1u;      // fp32 (expected)
        else if (w == 0x3C003C00u) cls = 2u; // fp16 pair
        flags[9] = cls;
        u32 acc = 0u;
        for (int i = 0; i < 2048; ++i) acc |= e[2 * i + 1];
        flags[8] = (acc != 0u) ? 1u : 0u;    // 0 => int64 (expected)
    }
}

__device__ __forceinline__ int ld_src(const int* e, int is64, size_t i) {
    return (is64 ? e[2 * i] : e[i]) & (NN - 1);
}
__device__ __forceinline__ int ld_dst(const int* e, int is64, size_t i) {
    return (is64 ? e[2 * ((size_t)E_TOT + i)] : e[(size_t)E_TOT + i]) & (NN - 1);
}
__device__ __forceinline__ int ld_y(const int* y, int is64, int bi) {
    return (is64 ? y[2 * bi] : y[bi]) & 1;
}

__global__ void cvt_kernel(const u16* s16, const float* s32, float* dst, int n,
                           const u32* flags) {
    const int i = blockIdx.x * 256 + threadIdx.x;
    if (i >= n) return;
    const u32 cls = flags[9];
    float v;
    if (cls == 1u) v = s32[i];
    else if (cls == 2u) v = f16u2f(s16[i]);
    else v = __uint_as_float(((u32)s16[i]) << 16);
    dst[i] = v;
}

// ---- CSR build (dst-sorted), one block per batch. DEDICATED global storage. ----
__global__ __launch_bounds__(256) void csr_kernel(const int* __restrict__ eidx,
                                                  const u32* __restrict__ flags,
                                                  u16* __restrict__ sortedD,
                                                  u32* __restrict__ rpD) {
    __shared__ u32 cntD[512];
    __shared__ u32 offD[512];
    __shared__ u32 p[256];
    const int bi = blockIdx.x;
    const int t = threadIdx.x;
    const int is64 = (flags[8] == 0u);
    for (int i = t; i < 512; i += 256) cntD[i] = 0u;
    __syncthreads();
    const size_t eb = (size_t)bi * EPER_C;
    for (int e = t; e < EPER_C; e += 256) {
        const int dl = ld_dst(eidx, is64, eb + e) & 511;
        atomicAdd(&cntD[dl], 1u);
    }
    __syncthreads();
    const u32 a0 = cntD[2 * t], a1 = cntD[2 * t + 1];
    p[t] = a0 + a1;
    __syncthreads();
    for (int d = 1; d < 256; d <<= 1) {
        u32 va = p[t];
        if (t >= d) va += p[t - d];
        __syncthreads();
        p[t] = va;
        __syncthreads();
    }
    {
        const u32 exD = p[t] - (a0 + a1);
        offD[2 * t] = exD;
        offD[2 * t + 1] = exD + a0;
    }
    __syncthreads();
    for (int i = t; i < 512; i += 256) rpD[bi * 513 + i] = offD[i];
    if (t == 0) rpD[bi * 513 + 512] = EPER_C;
    for (int i = t; i < 512; i += 256) cntD[i] = 0u;
    __syncthreads();
    for (int e = t; e < EPER_C; e += 256) {
        const int sl = ld_src(eidx, is64, eb + e) & 511;
        const int dl = ld_dst(eidx, is64, eb + e) & 511;
        const u32 pos = offD[dl] + atomicAdd(&cntD[dl], 1u);
        sortedD[eb + pos] = (u16)sl;
    }
}

// GEMM: Y[n][c] = sum_k X[n][k] * W[k][c], K=C=128.
__global__ __launch_bounds__(256) void gemm_k(const u32* __restrict__ X2,
                                              const float* __restrict__ Wc,
                                              u32* __restrict__ Y2,
                                              const u32* __restrict__ flags,
                                              int xmode, int hf32) {
    __shared__ float xs[64 * 129];
    __shared__ float wsm[128 * 32];
    const int n0 = blockIdx.x * 64;
    const int c0 = blockIdx.y * 32;
    const int t = threadIdx.x;
    if (xmode) {
        const u32 cls = flags[9];
        if (cls == 1u) {
            for (int idx = t; idx < 64 * 32; idx += 256) {
                const int r = idx >> 5, q = idx & 31;
                const float4 v = ((const float4*)X2)[(size_t)(n0 + r) * 32 + q];
                float* xd = &xs[r * 129 + q * 4];
                xd[0] = v.x; xd[1] = v.y; xd[2] = v.z; xd[3] = v.w;
            }
        } else if (cls == 2u) {
            for (int idx = t; idx < 64 * 16; idx += 256) {
                const int r = idx >> 4, q = idx & 15;
                const uint4 v = ((const uint4*)X2)[(size_t)(n0 + r) * 16 + q];
                float* xd = &xs[r * 129 + q * 8];
                xd[0] = f16u2f((u16)(v.x & 0xFFFFu)); xd[1] = f16u2f((u16)(v.x >> 16));
                xd[2] = f16u2f((u16)(v.y & 0xFFFFu)); xd[3] = f16u2f((u16)(v.y >> 16));
                xd[4] = f16u2f((u16)(v.z & 0xFFFFu)); xd[5] = f16u2f((u16)(v.z >> 16));
                xd[6] = f16u2f((u16)(v.w & 0xFFFFu)); xd[7] = f16u2f((u16)(v.w >> 16));
            }
        } else {
            for (int idx = t; idx < 64 * 16; idx += 256) {
                const int r = idx >> 4, q = idx & 15;
                const uint4 v = ((const uint4*)X2)[(size_t)(n0 + r) * 16 + q];
                float* xd = &xs[r * 129 + q * 8];
                xd[0] = bfu2f_lo(v.x); xd[1] = bfu2f_hi(v.x);
                xd[2] = bfu2f_lo(v.y); xd[3] = bfu2f_hi(v.y);
                xd[4] = bfu2f_lo(v.z); xd[5] = bfu2f_hi(v.z);
                xd[6] = bfu2f_lo(v.w); xd[7] = bfu2f_hi(v.w);
            }
        }
    } else {
        for (int idx = t; idx < 64 * 64; idx += 256) {
            const int r = idx >> 6, q = idx & 63;
            const float2 v = h_ld2(X2, (size_t)(n0 + r) * 64 + q, hf32);
            xs[r * 129 + 2 * q] = v.x;
            xs[r * 129 + 2 * q + 1] = v.y;
        }
    }
    for (int idx = t; idx < 128 * 32; idx += 256) {
        const int k = idx >> 5, cc = idx & 31;
        wsm[idx] = Wc[(size_t)k * 128 + c0 + cc];
    }
    __syncthreads();
    const int tx = t & 15, ty = t >> 4;
    const int cl = tx * 2, rl = ty * 4;
    float a00 = 0.f, a01 = 0.f, a10 = 0.f, a11 = 0.f;
    float a20 = 0.f, a21 = 0.f, a30 = 0.f, a31 = 0.f;
    for (int k = 0; k < 128; ++k) {
        const float w0 = wsm[k * 32 + cl];
        const float w1 = wsm[k * 32 + cl + 1];
        const float x0 = xs[(rl + 0) * 129 + k];
        const float x1 = xs[(rl + 1) * 129 + k];
        const float x2 = xs[(rl + 2) * 129 + k];
        const float x3 = xs[(rl + 3) * 129 + k];
        a00 += x0 * w0; a01 += x0 * w1;
        a10 += x1 * w0; a11 += x1 * w1;
        a20 += x2 * w0; a21 += x2 * w1;
        a30 += x3 * w0; a31 += x3 * w1;
    }
    const size_t pc = (size_t)(c0 >> 1) + tx;
    h_st2(Y2, (size_t)(n0 + rl + 0) * 64 + pc, a00, a01, hf32);
    h_st2(Y2, (size_t)(n0 + rl + 1) * 64 + pc, a10, a11, hf32);
    h_st2(Y2, (size_t)(n0 + rl + 2) * 64 + pc, a20, a21, hf32);
    h_st2(Y2, (size_t)(n0 + rl + 3) * 64 + pc, a30, a31, hf32);
}

// ---- GCN aggregation as GATHER (no atomics): h[l] = sum_{e: dst=l} m[src[e]] ----
__global__ __launch_bounds__(256) void gcn_gather_k(const u16* __restrict__ sortedD,
                                                    const u32* __restrict__ rpD,
                                                    const float* __restrict__ bias,
                                                    u32* M2,
                                                    float* __restrict__ bnacc,
                                                    int col_base, int hf32) {
    __shared__ u16 srt[EPER_C];     // 16 KB
    __shared__ u32 rp[513];         // 2 KB
    __shared__ float red[256 * 4];  // 4 KB
    const int bi = blockIdx.x >> 3;
    const int fc = blockIdx.x & 7;
    const int t = threadIdx.x;
    const u32* srcw = (const u32*)(sortedD + (size_t)bi * EPER_C);
    for (int i = t; i < EPER_C / 2; i += 256) ((u32*)srt)[i] = srcw[i];
    for (int i = t; i < 513; i += 256) rp[i] = rpD[bi * 513 + i];
    __syncthreads();
    const int j2 = t & 7;
    const int g = t >> 3;
    const size_t rowbase = (size_t)bi * 512;
    const size_t colp = (size_t)fc * 8 + j2;
    float a0[16], a1[16];
#pragma unroll
    for (int gi = 0; gi < 16; ++gi) {
        const int l = g + gi * 32;
        u32 r1 = rp[l + 1];
        if (r1 > EPER_C) r1 = EPER_C;   // safety clamp
        u32 r0 = rp[l];
        if (r0 > r1) r0 = r1;
        float s0 = 0.f, s1 = 0.f;
        for (u32 idx = r0; idx < r1; ++idx) {
            const int s = srt[idx];
            const float2 v = h_ld2(M2, (rowbase + s) * 64 + colp, hf32);
            s0 += v.x;
            s1 += v.y;
        }
        a0[gi] = s0;
        a1[gi] = s1;
    }
    __syncthreads();  // all reads of M complete before any write
    const float b0 = bias[fc * 16 + 2 * j2 + 0];
    const float b1 = bias[fc * 16 + 2 * j2 + 1];
    float S0 = 0.f, S1 = 0.f, Q0 = 0.f, Q1 = 0.f;
#pragma unroll
    for (int gi = 0; gi < 16; ++gi) {
        const int l = g + gi * 32;
        float v0 = san(a0[gi] + b0);
        float v1 = san(a1[gi] + b1);
        v0 = v0 > 0.f ? v0 : 0.f;
        v1 = v1 > 0.f ? v1 : 0.f;
        h_st2(M2, (rowbase + l) * 64 + colp, v0, v1, hf32);
        S0 += v0; S1 += v1; Q0 += v0 * v0; Q1 += v1 * v1;
    }
    red[t * 4 + 0] = S0;
    red[t * 4 + 1] = S1;
    red[t * 4 + 2] = Q0;
    red[t * 4 + 3] = Q1;
    __syncthreads();
    if (t < 32) {
        const int jp = t & 7;
        const int b = (t >> 3) & 1;
        const int sg = (t >> 4) & 1;
        float sum = 0.f;
        for (int gg = 0; gg < 32; ++gg) sum += red[(gg * 8 + jp) * 4 + sg * 2 + b];
        atomicAdd(&bnacc[(size_t)(col_base + fc * 16 + 2 * jp + b) * 2 + sg], sum);
    }
}

__global__ __launch_bounds__(384) void bn2_kernel(const float* __restrict__ bnacc,
                                                  const float* __restrict__ gamma,
                                                  const float* __restrict__ beta,
                                                  float* __restrict__ scaleA,
                                                  float* __restrict__ shiftA) {
    const int c = threadIdx.x;
    const float s = bnacc[c * 2 + 0];
    const float s2 = bnacc[c * 2 + 1];
    const float inv_n = 1.f / (float)NN;
    const float mu = san(s * inv_n);
    float var = san(s2 * inv_n - mu * mu);
    var = var > 0.f ? var : 0.f;
    const float sc = san(gamma[c] / sqrtf(var + BN_EPS_F));
    scaleA[c] = sc;
    shiftA[c] = san(beta[c] - mu * sc);
}

__global__ __launch_bounds__(256) void dist_kernel(const u32* __restrict__ h1,
                                                   const u32* __restrict__ h2,
                                                   const u32* __restrict__ h3,
                                                   const float* __restrict__ kc,
                                                   const float* __restrict__ scaleA,
                                                   const float* __restrict__ shiftA,
                                                   float4* __restrict__ Sf4, int hf32) {
    __shared__ float k2f[15 * 384];
    __shared__ float scl[384], shf[384];
    __shared__ float ksq[15];
    const int t = threadIdx.x;
    for (int i = t; i < 15 * 384; i += 256) k2f[i] = kc[i];
    for (int i = t; i < 384; i += 256) {
        scl[i] = scaleA[i];
        shf[i] = shiftA[i];
    }
    __syncthreads();
    if (t < 15) {
        float q = 0.f;
        for (int c2 = 0; c2 < 384; ++c2) {
            const float v = k2f[t * 384 + c2];
            q += v * v;
        }
        ksq[t] = q;
    }
    __syncthreads();
    const int n = blockIdx.x * 256 + t;
    float acc[15];
#pragma unroll
    for (int j = 0; j < 15; ++j) acc[j] = 0.f;
    float xq = 0.f;
#pragma unroll
    for (int pL = 0; pL < 3; ++pL) {
        const u32* hp = (pL == 0) ? h1 : (pL == 1) ? h2 : h3;
        const size_t rowp = (size_t)n * 64;
        for (int q8 = 0; q8 < 16; ++q8) {
            float xv[8];
#pragma unroll
            for (int j2 = 0; j2 < 4; ++j2) {
                const float2 v = h_ld2(hp, rowp + q8 * 4 + j2, hf32);
                xv[2 * j2] = v.x;
                xv[2 * j2 + 1] = v.y;
            }
            const int c = pL * 128 + q8 * 8;
#pragma unroll
            for (int i = 0; i < 8; ++i) {
                const float x = xv[i] * scl[c + i] + shf[c + i];
                xv[i] = x;
                xq += x * x;
            }
#pragma unroll
            for (int j = 0; j < 15; ++j) {
                const float* kr = &k2f[j * 384 + c];
                float a = acc[j];
#pragma unroll
                for (int i = 0; i < 8; ++i) a += xv[i] * kr[i];
                acc[j] = a;
            }
        }
    }
    float dist[15];
#pragma unroll
    for (int j = 0; j < 15; ++j) {
        float d2 = san(ksq[j] + xq - 2.f * acc[j]);
        d2 = d2 > 0.f ? d2 : 0.f;
        dist[j] = 1.f / (1.f + d2);
    }
    float S0 = 0.f, S1 = 0.f, S2 = 0.f;
#pragma unroll
    for (int h = 0; h < 5; ++h) {
        const float a = dist[h * 3 + 0], b = dist[h * 3 + 1], cd = dist[h * 3 + 2];
        const float inv = 1.f / fmaxf(a + b + cd, 1e-30f);
        S0 += a * inv;
        S1 += b * inv;
        S2 += cd * inv;
    }
    float4 o;
    o.x = san(S0); o.y = san(S1); o.z = san(S2); o.w = 0.f;
    Sf4[n] = o;
}

__global__ __launch_bounds__(256) void sagg_kernel(const int* __restrict__ eidx,
                                                   const u32* __restrict__ flags,
                                                   const float4* __restrict__ Sf4,
                                                   const int* __restrict__ y,
                                                   int* __restrict__ nodeK,
                                                   float* __restrict__ nodeW,
                                                   float* __restrict__ scal) {
    __shared__ float sacc[512 * 3];
    __shared__ unsigned int degc[512];
    __shared__ float rA[256], rB[256];
    const int bi = blockIdx.x;
    const int t = threadIdx.x;
    const int is64 = (flags[8] == 0u);
    for (int i = t; i < 512 * 3; i += 256) sacc[i] = 0.f;
    for (int i = t; i < 512; i += 256) degc[i] = 0u;
    __syncthreads();
    const size_t eb = (size_t)bi * EPER_C;
    for (int e = t; e < EPER_C; e += 256) {
        const int sg = ld_src(eidx, is64, eb + e);
        const int dg = ld_dst(eidx, is64, eb + e);
        const int sl = sg & 511;
        const int dl = dg & 511;
        const float4 sv = Sf4[dg];
        atomicAdd(&sacc[sl * 3 + 0], sv.x);
        atomicAdd(&sacc[sl * 3 + 1], sv.y);
        atomicAdd(&sacc[sl * 3 + 2], sv.z);
        atomicAdd(&degc[sl], 1u);
        atomicAdd(&degc[dl], 1u);
    }
    __syncthreads();
    float mfAcc = 0.f, slAcc = 0.f;
    for (int l = t; l < 512; l += 256) {
        const float cnt = (float)degc[l];
        const float degf = cnt > 0.f ? cnt * 0.5f : 1.f;
        const float inv = 1.f / degf;
        const float r0 = san(sacc[l * 3 + 0] * inv);
        const float r1 = san(sacc[l * 3 + 1] * inv);
        const float r2 = san(sacc[l * 3 + 2] * inv);
        int am = 0;
        float mx = r0;
        if (r1 > mx) { mx = r1; am = 1; }
        if (r2 > mx) { mx = r2; am = 2; }
        const float e0 = expf(r0 - mx), e1 = expf(r1 - mx), e2 = expf(r2 - mx);
        const float g = san(1.f / (e0 + e1 + e2));
        const int n = bi * 512 + l;
        nodeK[n] = am;
        nodeW[n] = g;
        if (am < 2) {
            mfAcc += 1.f;
            slAcc += g;
        }
    }
    rA[t] = mfAcc;
    rB[t] = slAcc;
    __syncthreads();
    for (int sft = 128; sft > 0; sft >>= 1) {
        if (t < sft) {
            rA[t] += rA[t + sft];
            rB[t] += rB[t + sft];
        }
        __syncthreads();
    }
    if (t == 0) {
        atomicAdd(&scal[ld_y(y, is64, bi)], rA[0]);
        atomicAdd(&scal[2], rB[0]);
    }
}

__global__ __launch_bounds__(256) void ce_kernel(const int* __restrict__ nodeK,
                                                 const float* __restrict__ nodeW,
                                                 const u32* __restrict__ flags,
                                                 const int* __restrict__ y,
                                                 float* __restrict__ scal) {
    const int n = blockIdx.x * 256 + threadIdx.x;
    const int bi = n >> 9;
    const int is64 = (flags[8] == 0u);
    const int kn = nodeK[n];
    float wce = 0.f, wsum = 0.f;
    if (kn >= 0 && kn < 2) {
        const float w = nodeW[n];
        const int yb = ld_y(y, is64, bi);
        const float l0 = (kn == 0) ? w : 0.f;
        const float l1 = (kn == 1) ? w : 0.f;
        const float m = fmaxf(l0, l1);
        const float lz = m + logf(expf(l0 - m) + expf(l1 - m));
        const float ce = lz - ((yb == 0) ? l0 : l1);
        const float bc0 = 1.f + scal[0];
        const float bc1 = 1.f + scal[1];
        const float bmax = fmaxf(bc0, bc1);
        const float wt = bmax / (((yb == 0) ? bc0 : bc1) + 0.001f);
        wce = san(wt * ce);
        wsum = san(wt);
    }
    __shared__ float rA[256], rB[256];
    const int t = threadIdx.x;
    rA[t] = wce;
    rB[t] = wsum;
    __syncthreads();
    for (int sft = 128; sft > 0; sft >>= 1) {
        if (t < sft) {
            rA[t] += rA[t + sft];
            rB[t] += rB[t + sft];
        }
        __syncthreads();
    }
    if (t == 0) {
        atomicAdd(&scal[3], rA[0]);
        atomicAdd(&scal[4], rB[0]);
    }
}

__global__ __launch_bounds__(192) void xp_kernel(const u32* __restrict__ h1,
                                                 const u32* __restrict__ h2,
                                                 const u32* __restrict__ h3,
                                                 const float* __restrict__ scaleA,
                                                 const float* __restrict__ shiftA,
                                                 const int* __restrict__ nodeK,
                                                 const float* __restrict__ nodeW,
                                                 float* __restrict__ xp, int hf32) {
    const int bi = blockIdx.x >> 1;
    const int half = blockIdx.x & 1;
    const int c = half * 192 + threadIdx.x;
    const u32* harr = (c < 128) ? h1 : (c < 256) ? h2 : h3;
    const int cc = c & 127;
    const float sc = scaleA[c], sh = shiftA[c];
    float a0 = 0.f, a1 = 0.f;
    const int nb = bi * 512;
    for (int l = 0; l < 512; ++l) {
        const int kn = nodeK[nb + l];
        if (kn >= 0 && kn < 2) {
            const float w = nodeW[nb + l];
            const float xv = h_ld1(harr, (size_t)(nb + l) * 128 + cc, hf32) * sc + sh;
            if (kn == 0) a0 += w * xv; else a1 += w * xv;
        }
    }
    xp[((size_t)bi * 2 + 0) * 384 + c] = san(a0);
    xp[((size_t)bi * 2 + 1) * 384 + c] = san(a1);
}

__global__ __launch_bounds__(128) void head_kernel(const float* __restrict__ xp,
                                                   const float* __restrict__ lpW,
                                                   const float* __restrict__ l1W,
                                                   const float* __restrict__ l1b,
                                                   const float* __restrict__ l2W,
                                                   const float* __restrict__ l2b,
                                                   float* __restrict__ outp) {
    const int bi = blockIdx.x;
    const int t = threadIdx.x;
    __shared__ float xfl[32];
    __shared__ float hidl[128];
    if (t < 32) {
        const int kk = t >> 4, o = t & 15;
        const float* xr = xp + ((size_t)bi * 2 + kk) * 384;
        float acc = 0.f;
        for (int c2 = 0; c2 < 384; ++c2) acc += xr[c2] * lpW[c2 * 16 + o];
        xfl[t] = san(acc);
    }
    __syncthreads();
    float acc = l1b[t];
    for (int i = 0; i < 32; ++i) acc += xfl[i] * l1W[i * 128 + t];
    hidl[t] = fmaxf(san(acc), 0.f);
    __syncthreads();
    if (t == 0) {
        float L0 = l2b[0], L1v = l2b[1];
        for (int j = 0; j < 128; ++j) {
            const float h = hidl[j];
            L0 += h * l2W[j * 2 + 0];
            L1v += h * l2W[j * 2 + 1];
        }
        L0 = san(L0); L1v = san(L1v);
        const float m = fmaxf(L0, L1v);
        const float ls = m + logf(expf(L0 - m) + expf(L1v - m));
        outp[bi * 2 + 0] = san(L0 - ls);
        outp[bi * 2 + 1] = san(L1v - ls);
    }
}

__global__ void fin_kernel(const float* __restrict__ scal, float* __restrict__ outp) {
    const float cel = san(scal[3] / fmaxf(scal[4], 1e-12f));
    const float total = san(10.f * cel + 0.01f * (scal[2] / (float)BB));
    outp[BB * 2] = total;
}

extern "C" void kernel_launch(void* const* d_in, const int* in_sizes, int n_in,
                              void* d_out, int out_size, void* d_ws, size_t ws_size,
                              hipStream_t stream) {
    (void)in_sizes; (void)n_in; (void)out_size;
    float* outp = (float*)d_out;

    // tail: Sf4 + nodeW + nodeK + xp + scal/flags + bnacc + scale/shift + canon
    //       + DEDICATED rpD (128*513 u32) + sortedD (E_TOT u16 = E_TOT/2 words)
    const size_t tailW = (size_t)NN * 4 + (size_t)NN + (size_t)NN + 98304 + 16 + 768 + 768
                       + 66690 + 128 * 513 + (size_t)E_TOT / 2;
    const size_t needF = 3ull * NN * 128ull * 4ull + tailW * 4ull;  // ~105.3 MB
    const size_t needB = 3ull * NN * 128ull * 2ull + tailW * 4ull;  // ~54.9 MB
    int hf32;
    if (ws_size >= needF) hf32 = 1;
    else if (ws_size >= needB) hf32 = 0;
    else {
        fill_out_kernel<<<2, 256, 0, stream>>>(outp, 2000.f + (float)(ws_size >> 20));
        return;
    }

    const u32* xw = (const u32*)d_in[0];
    const int* eidx = (const int*)d_in[1];
    const int* y = (const int*)d_in[2];

    const size_t esz = hf32 ? 4u : 2u;
    char* base = (char*)d_ws;
    u32* H1 = (u32*)base;
    u32* H2 = (u32*)(base + (size_t)NN * 128 * esz);
    u32* H3 = (u32*)(base + 2 * (size_t)NN * 128 * esz);
    float* fb = (float*)(base + 3 * (size_t)NN * 128 * esz);
    float4* Sf4 = (float4*)fb;                   // NN*4 words
    float* nodeW = fb + (size_t)NN * 4;          // NN words
    int* nodeK = (int*)(nodeW + NN);             // NN words
    float* xp = (float*)(nodeK + NN);            // 98304
    float* scal = xp + 98304;                    // 16 u32
    u32* flags = (u32*)scal;
    float* bnacc = scal + 16;                    // 768
    float* scaleA = bnacc + 768;                 // 384
    float* shiftA = scaleA + 384;                // 384
    float* canon = shiftA + 384;                 // 66690
    u32* rpD = (u32*)(canon + 66690);            // 128*513 words (dedicated)
    u16* sortedD = (u16*)(rpD + 128 * 513);      // E_TOT u16 (dedicated)

    init_kernel<<<4, 256, 0, stream>>>(flags, 784);
    probe_kernel<<<1, 64, 0, stream>>>((const u32*)d_in[9], (const u32*)eidx, flags);
    csr_kernel<<<BB, 256, 0, stream>>>(eidx, flags, sortedD, rpD);

    const int psz[14] = {16384, 128, 16384, 128, 16384, 128, 384, 384,
                         5760, 6144, 4096, 128, 256, 2};
    const int pof[14] = {0, 16384, 16512, 32896, 33024, 49408, 49536, 49920,
                         50304, 56064, 62208, 66304, 66432, 66688};
    for (int i = 0; i < 14; ++i) {
        cvt_kernel<<<(psz[i] + 255) / 256, 256, 0, stream>>>(
            (const u16*)d_in[3 + i], (const float*)d_in[3 + i],
            canon + pof[i], psz[i], flags);
    }

    gemm_k<<<dim3(NN / 64, 4), 256, 0, stream>>>(xw, canon + 0, H1, flags, 1, hf32);
    gcn_gather_k<<<BB * 8, 256, 0, stream>>>(sortedD, rpD, canon + 16384, H1, bnacc, 0, hf32);
    gemm_k<<<dim3(NN / 64, 4), 256, 0, stream>>>(H1, canon + 16512, H2, flags, 0, hf32);
    gcn_gather_k<<<BB * 8, 256, 0, stream>>>(sortedD, rpD, canon + 32896, H2, bnacc, 128, hf32);
    gemm_k<<<dim3(NN / 64, 4), 256, 0, stream>>>(H2, canon + 33024, H3, flags, 0, hf32);
    gcn_gather_k<<<BB * 8, 256, 0, stream>>>(sortedD, rpD, canon + 49408, H3, bnacc, 256, hf32);
    bn2_kernel<<<1, 384, 0, stream>>>(bnacc, canon + 49536, canon + 49920, scaleA, shiftA);
    dist_kernel<<<NN / 256, 256, 0, stream>>>(H1, H2, H3, canon + 50304, scaleA, shiftA,
                                              Sf4, hf32);
    sagg_kernel<<<BB, 256, 0, stream>>>(eidx, flags, Sf4, y, nodeK, nodeW, scal);
    ce_kernel<<<NN / 256, 256, 0, stream>>>(nodeK, nodeW, flags, y, scal);
    xp_kernel<<<BB * 2, 192, 0, stream>>>(H1, H2, H3, scaleA, shiftA, nodeK, nodeW, xp, hf32);
    head_kernel<<<BB, 128, 0, stream>>>(xp, canon + 56064, canon + 62208, canon + 66304,
                                        canon + 66432, canon + 66688, outp);
    fin_kernel<<<1, 1, 0, stream>>>(scal, outp);
}

// Round 13
// 982.286 us; speedup vs baseline: 2.6896x; 1.1104x over previous
//
#include <hip/hip_runtime.h>
#include <hip/hip_bf16.h>

#define BB 128
#define NV 512
#define NN (BB*NV)
#define EPER_C 8192
#define E_TOT (BB*EPER_C)
#define BN_EPS_F 1e-5f

typedef unsigned int u32;
typedef unsigned short u16;

__device__ __forceinline__ float bfu2f_lo(u32 w) { return __uint_as_float(w << 16); }
__device__ __forceinline__ float bfu2f_hi(u32 w) { return __uint_as_float(w & 0xFFFF0000u); }
__device__ __forceinline__ u16 f2bf(float f) {
    u32 u = __float_as_uint(f);
    u32 r = (u + 0x7FFFu + ((u >> 16) & 1u)) >> 16;
    return (u16)r;
}
__device__ __forceinline__ u32 pack2(float a, float b) {
    return (u32)f2bf(a) | ((u32)f2bf(b) << 16);
}
__device__ __forceinline__ float f16u2f(u16 h) {
    const u32 s = ((u32)h & 0x8000u) << 16;
    const u32 e = (h >> 10) & 0x1Fu;
    const u32 m = h & 0x3FFu;
    if (e == 0u) {
        float v = (float)m * 5.9604644775390625e-8f;
        return s ? -v : v;
    }
    if (e == 31u) return __uint_as_float(s | 0x7F800000u | (m << 13));
    return __uint_as_float(s | ((e + 112u) << 23) | (m << 13));
}
__device__ __forceinline__ float san(float v) {
    if (!(v == v)) return 0.f;
    return fminf(fmaxf(v, -1e30f), 1e30f);
}

// H storage: hf32=1 fp32, hf32=0 packed bf16. i2 = pair index (2 elems).
__device__ __forceinline__ float2 h_ld2(const u32* H, size_t i2, int hf32) {
    float2 v;
    if (hf32) {
        v = ((const float2*)H)[i2];
    } else {
        const u32 w = H[i2];
        v.x = bfu2f_lo(w);
        v.y = bfu2f_hi(w);
    }
    return v;
}
__device__ __forceinline__ void h_st2(u32* H, size_t i2, float a, float b, int hf32) {
    if (hf32) {
        float2 v;
        v.x = a;
        v.y = b;
        ((float2*)H)[i2] = v;
    } else {
        H[i2] = pack2(a, b);
    }
}
__device__ __forceinline__ float h_ld1(const u32* H, size_t i, int hf32) {
    if (hf32) return ((const float*)H)[i];
    return __uint_as_float(((u32)((const u16*)H)[i]) << 16);
}

// OUTPUT IS FLOAT32
__global__ void fill_out_kernel(float* o, float v) {
    int i = blockIdx.x * 256 + threadIdx.x;
    if (i < 257) o[i] = v;
}

// zero n u32 words
__global__ void init_kernel(u32* p, int n) {
    int i = blockIdx.x * 256 + threadIdx.x;
    if (i < n) p[i] = 0u;
}

__global__ void probe_kernel(const u32* g, const u32* e, u32* flags) {
    if (threadIdx.x == 0) {
        const u32 w = g[0];
        u32 cls = 0u;                        // bf16 pair 0x3F803F80
        if (w == 0x3F800000u) cls = 1u;      // fp32 (expected)
        else if (w == 0x3C003C00u) cls = 2u; // fp16 pair
        flags[9] = cls;
        u32 acc = 0u;
        for (int i = 0; i < 2048; ++i) acc |= e[2 * i + 1];
        flags[8] = (acc != 0u) ? 1u : 0u;    // 0 => int64 (expected)
    }
}

__device__ __forceinline__ int ld_src(const int* e, int is64, size_t i) {
    return (is64 ? e[2 * i] : e[i]) & (NN - 1);
}
__device__ __forceinline__ int ld_dst(const int* e, int is64, size_t i) {
    return (is64 ? e[2 * ((size_t)E_TOT + i)] : e[(size_t)E_TOT + i]) & (NN - 1);
}
__device__ __forceinline__ int ld_y(const int* y, int is64, int bi) {
    return (is64 ? y[2 * bi] : y[bi]) & 1;
}

__global__ void cvt_kernel(const u16* s16, const float* s32, float* dst, int n,
                           const u32* flags) {
    const int i = blockIdx.x * 256 + threadIdx.x;
    if (i >= n) return;
    const u32 cls = flags[9];
    float v;
    if (cls == 1u) v = s32[i];
    else if (cls == 2u) v = f16u2f(s16[i]);
    else v = __uint_as_float(((u32)s16[i]) << 16);
    dst[i] = v;
}

// ---- CSR build (dst-sorted), one block per batch. DEDICATED global storage. ----
__global__ __launch_bounds__(256) void csr_kernel(const int* __restrict__ eidx,
                                                  const u32* __restrict__ flags,
                                                  u16* __restrict__ sortedD,
                                                  u32* __restrict__ rpD) {
    __shared__ u32 cntD[512];
    __shared__ u32 offD[512];
    __shared__ u32 p[256];
    const int bi = blockIdx.x;
    const int t = threadIdx.x;
    const int is64 = (flags[8] == 0u);
    for (int i = t; i < 512; i += 256) cntD[i] = 0u;
    __syncthreads();
    const size_t eb = (size_t)bi * EPER_C;
    for (int e = t; e < EPER_C; e += 256) {
        const int dl = ld_dst(eidx, is64, eb + e) & 511;
        atomicAdd(&cntD[dl], 1u);
    }
    __syncthreads();
    const u32 a0 = cntD[2 * t], a1 = cntD[2 * t + 1];
    p[t] = a0 + a1;
    __syncthreads();
    for (int d = 1; d < 256; d <<= 1) {
        u32 va = p[t];
        if (t >= d) va += p[t - d];
        __syncthreads();
        p[t] = va;
        __syncthreads();
    }
    {
        const u32 exD = p[t] - (a0 + a1);
        offD[2 * t] = exD;
        offD[2 * t + 1] = exD + a0;
    }
    __syncthreads();
    for (int i = t; i < 512; i += 256) rpD[bi * 513 + i] = offD[i];
    if (t == 0) rpD[bi * 513 + 512] = EPER_C;
    for (int i = t; i < 512; i += 256) cntD[i] = 0u;
    __syncthreads();
    for (int e = t; e < EPER_C; e += 256) {
        const int sl = ld_src(eidx, is64, eb + e) & 511;
        const int dl = ld_dst(eidx, is64, eb + e) & 511;
        const u32 pos = offD[dl] + atomicAdd(&cntD[dl], 1u);
        sortedD[eb + pos] = (u16)sl;
    }
}

// GEMM: Y[n][c] = sum_k X[n][k] * W[k][c], K=C=128.
__global__ __launch_bounds__(256) void gemm_k(const u32* __restrict__ X2,
                                              const float* __restrict__ Wc,
                                              u32* __restrict__ Y2,
                                              const u32* __restrict__ flags,
                                              int xmode, int hf32) {
    __shared__ float xs[64 * 129];
    __shared__ float wsm[128 * 32];
    const int n0 = blockIdx.x * 64;
    const int c0 = blockIdx.y * 32;
    const int t = threadIdx.x;
    if (xmode) {
        const u32 cls = flags[9];
        if (cls == 1u) {
            for (int idx = t; idx < 64 * 32; idx += 256) {
                const int r = idx >> 5, q = idx & 31;
                const float4 v = ((const float4*)X2)[(size_t)(n0 + r) * 32 + q];
                float* xd = &xs[r * 129 + q * 4];
                xd[0] = v.x; xd[1] = v.y; xd[2] = v.z; xd[3] = v.w;
            }
        } else if (cls == 2u) {
            for (int idx = t; idx < 64 * 16; idx += 256) {
                const int r = idx >> 4, q = idx & 15;
                const uint4 v = ((const uint4*)X2)[(size_t)(n0 + r) * 16 + q];
                float* xd = &xs[r * 129 + q * 8];
                xd[0] = f16u2f((u16)(v.x & 0xFFFFu)); xd[1] = f16u2f((u16)(v.x >> 16));
                xd[2] = f16u2f((u16)(v.y & 0xFFFFu)); xd[3] = f16u2f((u16)(v.y >> 16));
                xd[4] = f16u2f((u16)(v.z & 0xFFFFu)); xd[5] = f16u2f((u16)(v.z >> 16));
                xd[6] = f16u2f((u16)(v.w & 0xFFFFu)); xd[7] = f16u2f((u16)(v.w >> 16));
            }
        } else {
            for (int idx = t; idx < 64 * 16; idx += 256) {
                const int r = idx >> 4, q = idx & 15;
                const uint4 v = ((const uint4*)X2)[(size_t)(n0 + r) * 16 + q];
                float* xd = &xs[r * 129 + q * 8];
                xd[0] = bfu2f_lo(v.x); xd[1] = bfu2f_hi(v.x);
                xd[2] = bfu2f_lo(v.y); xd[3] = bfu2f_hi(v.y);
                xd[4] = bfu2f_lo(v.z); xd[5] = bfu2f_hi(v.z);
                xd[6] = bfu2f_lo(v.w); xd[7] = bfu2f_hi(v.w);
            }
        }
    } else {
        for (int idx = t; idx < 64 * 64; idx += 256) {
            const int r = idx >> 6, q = idx & 63;
            const float2 v = h_ld2(X2, (size_t)(n0 + r) * 64 + q, hf32);
            xs[r * 129 + 2 * q] = v.x;
            xs[r * 129 + 2 * q + 1] = v.y;
        }
    }
    for (int idx = t; idx < 128 * 32; idx += 256) {
        const int k = idx >> 5, cc = idx & 31;
        wsm[idx] = Wc[(size_t)k * 128 + c0 + cc];
    }
    __syncthreads();
    const int tx = t & 15, ty = t >> 4;
    const int cl = tx * 2, rl = ty * 4;
    float a00 = 0.f, a01 = 0.f, a10 = 0.f, a11 = 0.f;
    float a20 = 0.f, a21 = 0.f, a30 = 0.f, a31 = 0.f;
    for (int k = 0; k < 128; ++k) {
        const float w0 = wsm[k * 32 + cl];
        const float w1 = wsm[k * 32 + cl + 1];
        const float x0 = xs[(rl + 0) * 129 + k];
        const float x1 = xs[(rl + 1) * 129 + k];
        const float x2 = xs[(rl + 2) * 129 + k];
        const float x3 = xs[(rl + 3) * 129 + k];
        a00 += x0 * w0; a01 += x0 * w1;
        a10 += x1 * w0; a11 += x1 * w1;
        a20 += x2 * w0; a21 += x2 * w1;
        a30 += x3 * w0; a31 += x3 * w1;
    }
    const size_t pc = (size_t)(c0 >> 1) + tx;
    h_st2(Y2, (size_t)(n0 + rl + 0) * 64 + pc, a00, a01, hf32);
    h_st2(Y2, (size_t)(n0 + rl + 1) * 64 + pc, a10, a11, hf32);
    h_st2(Y2, (size_t)(n0 + rl + 2) * 64 + pc, a20, a21, hf32);
    h_st2(Y2, (size_t)(n0 + rl + 3) * 64 + pc, a30, a31, hf32);
}

// ---- GCN aggregation as GATHER (no atomics): h[l] = sum_{e: dst=l} m[src[e]] ----
__global__ __launch_bounds__(256) void gcn_gather_k(const u16* __restrict__ sortedD,
                                                    const u32* __restrict__ rpD,
                                                    const float* __restrict__ bias,
                                                    u32* M2,
                                                    float* __restrict__ bnacc,
                                                    int col_base, int hf32) {
    __shared__ u16 srt[EPER_C];     // 16 KB
    __shared__ u32 rp[513];         // 2 KB
    __shared__ float red[256 * 4];  // 4 KB
    const int bi = blockIdx.x >> 3;
    const int fc = blockIdx.x & 7;
    const int t = threadIdx.x;
    const u32* srcw = (const u32*)(sortedD + (size_t)bi * EPER_C);
    for (int i = t; i < EPER_C / 2; i += 256) ((u32*)srt)[i] = srcw[i];
    for (int i = t; i < 513; i += 256) rp[i] = rpD[bi * 513 + i];
    __syncthreads();
    const int j2 = t & 7;
    const int g = t >> 3;
    const size_t rowbase = (size_t)bi * 512;
    const size_t colp = (size_t)fc * 8 + j2;
    float a0[16], a1[16];
#pragma unroll
    for (int gi = 0; gi < 16; ++gi) {
        const int l = g + gi * 32;
        u32 r1 = rp[l + 1];
        if (r1 > EPER_C) r1 = EPER_C;   // safety clamp
        u32 r0 = rp[l];
        if (r0 > r1) r0 = r1;
        float s0 = 0.f, s1 = 0.f;
        for (u32 idx = r0; idx < r1; ++idx) {
            const int s = srt[idx];
            const float2 v = h_ld2(M2, (rowbase + s) * 64 + colp, hf32);
            s0 += v.x;
            s1 += v.y;
        }
        a0[gi] = s0;
        a1[gi] = s1;
    }
    __syncthreads();  // all reads of M complete before any write
    const float b0 = bias[fc * 16 + 2 * j2 + 0];
    const float b1 = bias[fc * 16 + 2 * j2 + 1];
    float S0 = 0.f, S1 = 0.f, Q0 = 0.f, Q1 = 0.f;
#pragma unroll
    for (int gi = 0; gi < 16; ++gi) {
        const int l = g + gi * 32;
        float v0 = san(a0[gi] + b0);
        float v1 = san(a1[gi] + b1);
        v0 = v0 > 0.f ? v0 : 0.f;
        v1 = v1 > 0.f ? v1 : 0.f;
        h_st2(M2, (rowbase + l) * 64 + colp, v0, v1, hf32);
        S0 += v0; S1 += v1; Q0 += v0 * v0; Q1 += v1 * v1;
    }
    red[t * 4 + 0] = S0;
    red[t * 4 + 1] = S1;
    red[t * 4 + 2] = Q0;
    red[t * 4 + 3] = Q1;
    __syncthreads();
    if (t < 32) {
        const int jp = t & 7;
        const int b = (t >> 3) & 1;
        const int sg = (t >> 4) & 1;
        float sum = 0.f;
        for (int gg = 0; gg < 32; ++gg) sum += red[(gg * 8 + jp) * 4 + sg * 2 + b];
        atomicAdd(&bnacc[(size_t)(col_base + fc * 16 + 2 * jp + b) * 2 + sg], sum);
    }
}

__global__ __launch_bounds__(384) void bn2_kernel(const float* __restrict__ bnacc,
                                                  const float* __restrict__ gamma,
                                                  const float* __restrict__ beta,
                                                  float* __restrict__ scaleA,
                                                  float* __restrict__ shiftA) {
    const int c = threadIdx.x;
    const float s = bnacc[c * 2 + 0];
    const float s2 = bnacc[c * 2 + 1];
    const float inv_n = 1.f / (float)NN;
    const float mu = san(s * inv_n);
    float var = san(s2 * inv_n - mu * mu);
    var = var > 0.f ? var : 0.f;
    const float sc = san(gamma[c] / sqrtf(var + BN_EPS_F));
    scaleA[c] = sc;
    shiftA[c] = san(beta[c] - mu * sc);
}

__global__ __launch_bounds__(256) void dist_kernel(const u32* __restrict__ h1,
                                                   const u32* __restrict__ h2,
                                                   const u32* __restrict__ h3,
                                                   const float* __restrict__ kc,
                                                   const float* __restrict__ scaleA,
                                                   const float* __restrict__ shiftA,
                                                   float4* __restrict__ Sf4, int hf32) {
    __shared__ float k2f[15 * 384];
    __shared__ float scl[384], shf[384];
    __shared__ float ksq[15];
    const int t = threadIdx.x;
    for (int i = t; i < 15 * 384; i += 256) k2f[i] = kc[i];
    for (int i = t; i < 384; i += 256) {
        scl[i] = scaleA[i];
        shf[i] = shiftA[i];
    }
    __syncthreads();
    if (t < 15) {
        float q = 0.f;
        for (int c2 = 0; c2 < 384; ++c2) {
            const float v = k2f[t * 384 + c2];
            q += v * v;
        }
        ksq[t] = q;
    }
    __syncthreads();
    const int n = blockIdx.x * 256 + t;
    float acc[15];
#pragma unroll
    for (int j = 0; j < 15; ++j) acc[j] = 0.f;
    float xq = 0.f;
#pragma unroll
    for (int pL = 0; pL < 3; ++pL) {
        const u32* hp = (pL == 0) ? h1 : (pL == 1) ? h2 : h3;
        const size_t rowp = (size_t)n * 64;
        for (int q8 = 0; q8 < 16; ++q8) {
            float xv[8];
#pragma unroll
            for (int j2 = 0; j2 < 4; ++j2) {
                const float2 v = h_ld2(hp, rowp + q8 * 4 + j2, hf32);
                xv[2 * j2] = v.x;
                xv[2 * j2 + 1] = v.y;
            }
            const int c = pL * 128 + q8 * 8;
#pragma unroll
            for (int i = 0; i < 8; ++i) {
                const float x = xv[i] * scl[c + i] + shf[c + i];
                xv[i] = x;
                xq += x * x;
            }
#pragma unroll
            for (int j = 0; j < 15; ++j) {
                const float* kr = &k2f[j * 384 + c];
                float a = acc[j];
#pragma unroll
                for (int i = 0; i < 8; ++i) a += xv[i] * kr[i];
                acc[j] = a;
            }
        }
    }
    float dist[15];
#pragma unroll
    for (int j = 0; j < 15; ++j) {
        float d2 = san(ksq[j] + xq - 2.f * acc[j]);
        d2 = d2 > 0.f ? d2 : 0.f;
        dist[j] = 1.f / (1.f + d2);
    }
    float S0 = 0.f, S1 = 0.f, S2 = 0.f;
#pragma unroll
    for (int h = 0; h < 5; ++h) {
        const float a = dist[h * 3 + 0], b = dist[h * 3 + 1], cd = dist[h * 3 + 2];
        const float inv = 1.f / fmaxf(a + b + cd, 1e-30f);
        S0 += a * inv;
        S1 += b * inv;
        S2 += cd * inv;
    }
    float4 o;
    o.x = san(S0); o.y = san(S1); o.z = san(S2); o.w = 0.f;
    Sf4[n] = o;
}

__global__ __launch_bounds__(256) void sagg_kernel(const int* __restrict__ eidx,
                                                   const u32* __restrict__ flags,
                                                   const float4* __restrict__ Sf4,
                                                   const int* __restrict__ y,
                                                   int* __restrict__ nodeK,
                                                   float* __restrict__ nodeW,
                                                   float* __restrict__ scal) {
    __shared__ float sacc[512 * 3];
    __shared__ unsigned int degc[512];
    __shared__ float rA[256], rB[256];
    const int bi = blockIdx.x;
    const int t = threadIdx.x;
    const int is64 = (flags[8] == 0u);
    for (int i = t; i < 512 * 3; i += 256) sacc[i] = 0.f;
    for (int i = t; i < 512; i += 256) degc[i] = 0u;
    __syncthreads();
    const size_t eb = (size_t)bi * EPER_C;
    for (int e = t; e < EPER_C; e += 256) {
        const int sg = ld_src(eidx, is64, eb + e);
        const int dg = ld_dst(eidx, is64, eb + e);
        const int sl = sg & 511;
        const int dl = dg & 511;
        const float4 sv = Sf4[dg];
        atomicAdd(&sacc[sl * 3 + 0], sv.x);
        atomicAdd(&sacc[sl * 3 + 1], sv.y);
        atomicAdd(&sacc[sl * 3 + 2], sv.z);
        atomicAdd(&degc[sl], 1u);
        atomicAdd(&degc[dl], 1u);
    }
    __syncthreads();
    float mfAcc = 0.f, slAcc = 0.f;
    for (int l = t; l < 512; l += 256) {
        const float cnt = (float)degc[l];
        const float degf = cnt > 0.f ? cnt * 0.5f : 1.f;
        const float inv = 1.f / degf;
        const float r0 = san(sacc[l * 3 + 0] * inv);
        const float r1 = san(sacc[l * 3 + 1] * inv);
        const float r2 = san(sacc[l * 3 + 2] * inv);
        int am = 0;
        float mx = r0;
        if (r1 > mx) { mx = r1; am = 1; }
        if (r2 > mx) { mx = r2; am = 2; }
        const float e0 = expf(r0 - mx), e1 = expf(r1 - mx), e2 = expf(r2 - mx);
        const float g = san(1.f / (e0 + e1 + e2));
        const int n = bi * 512 + l;
        nodeK[n] = am;
        nodeW[n] = g;
        if (am < 2) {
            mfAcc += 1.f;
            slAcc += g;
        }
    }
    rA[t] = mfAcc;
    rB[t] = slAcc;
    __syncthreads();
    for (int sft = 128; sft > 0; sft >>= 1) {
        if (t < sft) {
            rA[t] += rA[t + sft];
            rB[t] += rB[t + sft];
        }
        __syncthreads();
    }
    if (t == 0) {
        atomicAdd(&scal[ld_y(y, is64, bi)], rA[0]);
        atomicAdd(&scal[2], rB[0]);
    }
}

__global__ __launch_bounds__(256) void ce_kernel(const int* __restrict__ nodeK,
                                                 const float* __restrict__ nodeW,
                                                 const u32* __restrict__ flags,
                                                 const int* __restrict__ y,
                                                 float* __restrict__ scal) {
    const int n = blockIdx.x * 256 + threadIdx.x;
    const int bi = n >> 9;
    const int is64 = (flags[8] == 0u);
    const int kn = nodeK[n];
    float wce = 0.f, wsum = 0.f;
    if (kn >= 0 && kn < 2) {
        const float w = nodeW[n];
        const int yb = ld_y(y, is64, bi);
        const float l0 = (kn == 0) ? w : 0.f;
        const float l1 = (kn == 1) ? w : 0.f;
        const float m = fmaxf(l0, l1);
        const float lz = m + logf(expf(l0 - m) + expf(l1 - m));
        const float ce = lz - ((yb == 0) ? l0 : l1);
        const float bc0 = 1.f + scal[0];
        const float bc1 = 1.f + scal[1];
        const float bmax = fmaxf(bc0, bc1);
        const float wt = bmax / (((yb == 0) ? bc0 : bc1) + 0.001f);
        wce = san(wt * ce);
        wsum = san(wt);
    }
    __shared__ float rA[256], rB[256];
    const int t = threadIdx.x;
    rA[t] = wce;
    rB[t] = wsum;
    __syncthreads();
    for (int sft = 128; sft > 0; sft >>= 1) {
        if (t < sft) {
            rA[t] += rA[t + sft];
            rB[t] += rB[t + sft];
        }
        __syncthreads();
    }
    if (t == 0) {
        atomicAdd(&scal[3], rA[0]);
        atomicAdd(&scal[4], rB[0]);
    }
}

// ---- pooling einsum v2: block=(batch, node-chunk of 128), thread=column. ----
// Coalesced row reads; nodeK/nodeW are block-uniform broadcasts; atomicAdd of
// per-chunk partials into zero-initialized xp.
__global__ __launch_bounds__(384) void xp_kernel(const u32* __restrict__ h1,
                                                 const u32* __restrict__ h2,
                                                 const u32* __restrict__ h3,
                                                 const float* __restrict__ scaleA,
                                                 const float* __restrict__ shiftA,
                                                 const int* __restrict__ nodeK,
                                                 const float* __restrict__ nodeW,
                                                 float* __restrict__ xp, int hf32) {
    const int bi = blockIdx.x >> 2;
    const int ch = blockIdx.x & 3;
    const int c = threadIdx.x;  // 0..383
    const u32* harr = (c < 128) ? h1 : (c < 256) ? h2 : h3;
    const int cc = c & 127;
    const float sc = scaleA[c], sh = shiftA[c];
    float a0 = 0.f, a1 = 0.f;
    const int nb = bi * 512 + ch * 128;
    for (int l = 0; l < 128; ++l) {
        const int kn = nodeK[nb + l];
        if (kn >= 0 && kn < 2) {
            const float w = nodeW[nb + l];
            const float xv = h_ld1(harr, (size_t)(nb + l) * 128 + cc, hf32) * sc + sh;
            if (kn == 0) a0 += w * xv; else a1 += w * xv;
        }
    }
    atomicAdd(&xp[((size_t)bi * 2 + 0) * 384 + c], san(a0));
    atomicAdd(&xp[((size_t)bi * 2 + 1) * 384 + c], san(a1));
}

__global__ __launch_bounds__(128) void head_kernel(const float* __restrict__ xp,
                                                   const float* __restrict__ lpW,
                                                   const float* __restrict__ l1W,
                                                   const float* __restrict__ l1b,
                                                   const float* __restrict__ l2W,
                                                   const float* __restrict__ l2b,
                                                   float* __restrict__ outp) {
    const int bi = blockIdx.x;
    const int t = threadIdx.x;
    __shared__ float xfl[32];
    __shared__ float hidl[128];
    if (t < 32) {
        const int kk = t >> 4, o = t & 15;
        const float* xr = xp + ((size_t)bi * 2 + kk) * 384;
        float acc = 0.f;
        for (int c2 = 0; c2 < 384; ++c2) acc += xr[c2] * lpW[c2 * 16 + o];
        xfl[t] = san(acc);
    }
    __syncthreads();
    float acc = l1b[t];
    for (int i = 0; i < 32; ++i) acc += xfl[i] * l1W[i * 128 + t];
    hidl[t] = fmaxf(san(acc), 0.f);
    __syncthreads();
    if (t == 0) {
        float L0 = l2b[0], L1v = l2b[1];
        for (int j = 0; j < 128; ++j) {
            const float h = hidl[j];
            L0 += h * l2W[j * 2 + 0];
            L1v += h * l2W[j * 2 + 1];
        }
        L0 = san(L0); L1v = san(L1v);
        const float m = fmaxf(L0, L1v);
        const float ls = m + logf(expf(L0 - m) + expf(L1v - m));
        outp[bi * 2 + 0] = san(L0 - ls);
        outp[bi * 2 + 1] = san(L1v - ls);
    }
}

__global__ void fin_kernel(const float* __restrict__ scal, float* __restrict__ outp) {
    const float cel = san(scal[3] / fmaxf(scal[4], 1e-12f));
    const float total = san(10.f * cel + 0.01f * (scal[2] / (float)BB));
    outp[BB * 2] = total;
}

extern "C" void kernel_launch(void* const* d_in, const int* in_sizes, int n_in,
                              void* d_out, int out_size, void* d_ws, size_t ws_size,
                              hipStream_t stream) {
    (void)in_sizes; (void)n_in; (void)out_size;
    float* outp = (float*)d_out;

    const size_t tailW = (size_t)NN * 4 + (size_t)NN + (size_t)NN + 98304 + 16 + 768 + 768
                       + 66690 + 128 * 513 + (size_t)E_TOT / 2;
    const size_t needF = 3ull * NN * 128ull * 4ull + tailW * 4ull;  // ~105.3 MB
    const size_t needB = 3ull * NN * 128ull * 2ull + tailW * 4ull;  // ~54.9 MB
    int hf32;
    if (ws_size >= needF) hf32 = 1;
    else if (ws_size >= needB) hf32 = 0;
    else {
        fill_out_kernel<<<2, 256, 0, stream>>>(outp, 2000.f + (float)(ws_size >> 20));
        return;
    }

    const u32* xw = (const u32*)d_in[0];
    const int* eidx = (const int*)d_in[1];
    const int* y = (const int*)d_in[2];

    const size_t esz = hf32 ? 4u : 2u;
    char* base = (char*)d_ws;
    u32* H1 = (u32*)base;
    u32* H2 = (u32*)(base + (size_t)NN * 128 * esz);
    u32* H3 = (u32*)(base + 2 * (size_t)NN * 128 * esz);
    float* fb = (float*)(base + 3 * (size_t)NN * 128 * esz);
    float4* Sf4 = (float4*)fb;                   // NN*4 words
    float* nodeW = fb + (size_t)NN * 4;          // NN words
    int* nodeK = (int*)(nodeW + NN);             // NN words
    float* xp = (float*)(nodeK + NN);            // 98304
    float* scal = xp + 98304;                    // 16 u32
    u32* flags = (u32*)scal;
    float* bnacc = scal + 16;                    // 768
    float* scaleA = bnacc + 768;                 // 384
    float* shiftA = scaleA + 384;                // 384
    float* canon = shiftA + 384;                 // 66690
    u32* rpD = (u32*)(canon + 66690);            // 128*513 words (dedicated)
    u16* sortedD = (u16*)(rpD + 128 * 513);      // E_TOT u16 (dedicated)

    init_kernel<<<4, 256, 0, stream>>>(flags, 784);
    init_kernel<<<384, 256, 0, stream>>>((u32*)xp, 98304);
    probe_kernel<<<1, 64, 0, stream>>>((const u32*)d_in[9], (const u32*)eidx, flags);
    csr_kernel<<<BB, 256, 0, stream>>>(eidx, flags, sortedD, rpD);

    const int psz[14] = {16384, 128, 16384, 128, 16384, 128, 384, 384,
                         5760, 6144, 4096, 128, 256, 2};
    const int pof[14] = {0, 16384, 16512, 32896, 33024, 49408, 49536, 49920,
                         50304, 56064, 62208, 66304, 66432, 66688};
    for (int i = 0; i < 14; ++i) {
        cvt_kernel<<<(psz[i] + 255) / 256, 256, 0, stream>>>(
            (const u16*)d_in[3 + i], (const float*)d_in[3 + i],
            canon + pof[i], psz[i], flags);
    }

    gemm_k<<<dim3(NN / 64, 4), 256, 0, stream>>>(xw, canon + 0, H1, flags, 1, hf32);
    gcn_gather_k<<<BB * 8, 256, 0, stream>>>(sortedD, rpD, canon + 16384, H1, bnacc, 0, hf32);
    gemm_k<<<dim3(NN / 64, 4), 256, 0, stream>>>(H1, canon + 16512, H2, flags, 0, hf32);
    gcn_gather_k<<<BB * 8, 256, 0, stream>>>(sortedD, rpD, canon + 32896, H2, bnacc, 128, hf32);
    gemm_k<<<dim3(NN / 64, 4), 256, 0, stream>>>(H2, canon + 33024, H3, flags, 0, hf32);
    gcn_gather_k<<<BB * 8, 256, 0, stream>>>(sortedD, rpD, canon + 49408, H3, bnacc, 256, hf32);
    bn2_kernel<<<1, 384, 0, stream>>>(bnacc, canon + 49536, canon + 49920, scaleA, shiftA);
    dist_kernel<<<NN / 256, 256, 0, stream>>>(H1, H2, H3, canon + 50304, scaleA, shiftA,
                                              Sf4, hf32);
    sagg_kernel<<<BB, 256, 0, stream>>>(eidx, flags, Sf4, y, nodeK, nodeW, scal);
    ce_kernel<<<NN / 256, 256, 0, stream>>>(nodeK, nodeW, flags, y, scal);
    xp_kernel<<<BB * 4, 384, 0, stream>>>(H1, H2, H3, scaleA, shiftA, nodeK, nodeW, xp, hf32);
    head_kernel<<<BB, 128, 0, stream>>>(xp, canon + 56064, canon + 62208, canon + 66304,
                                        canon + 66432, canon + 66688, outp);
    fin_kernel<<<1, 1, 0, stream>>>(scal, outp);
}